// Round 1
// baseline (86.109 us; speedup 1.0000x reference)
//
#include <hip/hip_runtime.h>
#include <math.h>

#define N_G   512
#define W_IMG 256
#define H_IMG 256

// Fully fused single-kernel 3DGS renderer.
// Each 1024-thread block (one 16x16 pixel tile):
//   phase 1: threads 0..511 project gaussian t -> params, rank-sort by depth
//            (stable, fused tie-break) into LDS s_params (depth order).
//   phase 2: waves 0..7 cull vs tile rect, compact survivors into s_p.
//   phase 3: 4-way depth-segmented front-to-back composite; exact combine
//            acc0 + T0*acc1 + T0*T1*acc2 + T0*T1*T2*acc3.
//
// params layout per gaussian (3 x float4 = 48B), depth-sorted:
//  p0 = (mean_x, mean_y, qa, qb)      expo = qa*dx^2 + qb*dx*dy + qd*dy^2
//  p1 = (qd, w, r2cut, col_r)         w = valid * opac / (2*pi*sqrt(det))
//  p2 = (col_g, col_b, 0, 0)          skip if dist^2(rect, mean) > r2cut

__global__ __launch_bounds__(1024) void gs_fused(
    const float* __restrict__ means3D, const float* __restrict__ covs3d,
    const float* __restrict__ colors,  const float* __restrict__ opac,
    const float* __restrict__ Km, const float* __restrict__ Rm,
    const float* __restrict__ tv, float* __restrict__ out)
{
    __shared__ unsigned int s_key[N_G];        //  2 KB
    __shared__ float4 s_params[N_G * 3];       // 24 KB, depth-sorted
    __shared__ float4 s_p[N_G * 3];            // 24 KB, culled+compacted
    __shared__ float4 s_part[3 * 256];         // 12 KB, segment partials
    __shared__ int    s_cnt[8];
    __shared__ int    s_off[9];

    const int tid  = threadIdx.x;
    const int wave = tid >> 6;
    const int lane = tid & 63;
    const int x0 = blockIdx.x * 16;
    const int y0 = blockIdx.y * 16;

    // ---------------- phase 1: projection (threads 0..511) ----------------
    float mx=0.f, my=0.f, qa=0.f, qb=0.f, qd=0.f, wv=0.f, r2cut=-1.f;
    float cr=0.f, cg=0.f, cb=0.f;
    unsigned int kb = 0u;

    if (tid < N_G) {
        const int t = tid;
        const float R00=Rm[0],R01=Rm[1],R02=Rm[2],
                    R10=Rm[3],R11=Rm[4],R12=Rm[5],
                    R20=Rm[6],R21=Rm[7],R22=Rm[8];
        const float K00=Km[0],K01=Km[1],K02=Km[2],
                    K10=Km[3],K11=Km[4],K12=Km[5],
                    K20=Km[6],K21=Km[7],K22=Km[8];
        const float t0=tv[0],t1=tv[1],t2=tv[2];

        const float m0=means3D[3*t], m1=means3D[3*t+1], m2=means3D[3*t+2];
        const float cx = R00*m0 + R01*m1 + R02*m2 + t0;
        const float cy = R10*m0 + R11*m1 + R12*m2 + t1;
        const float cz = R20*m0 + R21*m1 + R22*m2 + t2;
        const float depth = fmaxf(cz, 1.0f);

        const float s0 = K00*cx + K01*cy + K02*cz;
        const float s1 = K10*cx + K11*cy + K12*cz;
        const float s2 = K20*cx + K21*cy + K22*cz;
        mx = s0 / s2;
        my = s1 / s2;

        const float C00=covs3d[9*t+0], C01=covs3d[9*t+1], C02=covs3d[9*t+2];
        const float C10=covs3d[9*t+3], C11=covs3d[9*t+4], C12=covs3d[9*t+5];
        const float C20=covs3d[9*t+6], C21=covs3d[9*t+7], C22=covs3d[9*t+8];

        const float T00 = R00*C00 + R01*C10 + R02*C20;
        const float T01 = R00*C01 + R01*C11 + R02*C21;
        const float T02 = R00*C02 + R01*C12 + R02*C22;
        const float T10 = R10*C00 + R11*C10 + R12*C20;
        const float T11 = R10*C01 + R11*C11 + R12*C21;
        const float T12 = R10*C02 + R11*C12 + R12*C22;
        const float T20 = R20*C00 + R21*C10 + R22*C20;
        const float T21 = R20*C01 + R21*C11 + R22*C21;
        const float T22 = R20*C02 + R21*C12 + R22*C22;

        const float cc00 = T00*R00 + T01*R01 + T02*R02;
        const float cc01 = T00*R10 + T01*R11 + T02*R12;
        const float cc02 = T00*R20 + T01*R21 + T02*R22;
        const float cc10 = T10*R00 + T11*R01 + T12*R02;
        const float cc11 = T10*R10 + T11*R11 + T12*R12;
        const float cc12 = T10*R20 + T11*R21 + T12*R22;
        const float cc20 = T20*R00 + T21*R01 + T22*R02;
        const float cc21 = T20*R10 + T21*R11 + T22*R12;
        const float cc22 = T20*R20 + T21*R21 + T22*R22;

        const float fx = K00, fy = K11;
        const float invz = 1.0f / cz;
        const float J00 = fx * invz;
        const float J02 = -fx * cx * invz * invz;
        const float J11 = fy * invz;
        const float J12 = -fy * cy * invz * invz;

        const float U00 = J00*cc00 + J02*cc20;
        const float U01 = J00*cc01 + J02*cc21;
        const float U02 = J00*cc02 + J02*cc22;
        const float U10 = J11*cc10 + J12*cc20;
        const float U11 = J11*cc11 + J12*cc21;
        const float U12 = J11*cc12 + J12*cc22;

        const float a = U00*J00 + U02*J02 + 1e-4f;
        const float b = U01*J11 + U02*J12;
        const float c = U10*J00 + U12*J02;
        const float d = U11*J11 + U12*J12 + 1e-4f;

        const float det = a*d - b*c;
        const float ia  = d / det;
        const float id_ = a / det;
        const float sib = (b + c) / det;

        qa = -0.5f * ia;
        qb =  0.5f * sib;
        qd = -0.5f * id_;

        const bool valid = (depth > 1.0f) && (depth < 50.0f);
        const float norm = 0.15915494309189535f * rsqrtf(det);
        wv = valid ? opac[t] * norm : 0.0f;
        if (!(wv > 0.0f)) wv = 0.0f;

        const float hm  = 0.5f * (ia + id_);
        const float dh  = 0.5f * (ia - id_);
        const float off = 0.5f * sib;
        const float lmin = hm - sqrtf(dh*dh + off*off);

        // cull threshold tau = 1e-7: worst-case accumulated error <= 512*tau
        // = 5.1e-5, ~10x under the 4.96e-4 absmax threshold.
        if (wv <= 1e-7f)       r2cut = -1.0f;
        else if (lmin <= 0.f)  r2cut = 1e30f;
        else                   r2cut = 2.0f * __logf(wv * 1e7f) / lmin;

        cr = colors[3*t]; cg = colors[3*t+1]; cb = colors[3*t+2];

        kb = __float_as_uint(depth);   // depth > 0 -> bits monotone
        s_key[t] = kb;
    }
    __syncthreads();

    // rank-based stable sort, tie-break fused into the vectorized scan
    if (tid < N_G) {
        int rank = 0;
        const uint4* k4 = (const uint4*)s_key;
        #pragma unroll 4
        for (int j = 0; j < N_G / 4; ++j) {
            const uint4 k = k4[j];
            const int base = 4*j;
            rank += (int)(k.x < kb) + (int)((k.x == kb) && (base+0 < tid));
            rank += (int)(k.y < kb) + (int)((k.y == kb) && (base+1 < tid));
            rank += (int)(k.z < kb) + (int)((k.z == kb) && (base+2 < tid));
            rank += (int)(k.w < kb) + (int)((k.w == kb) && (base+3 < tid));
        }
        s_params[rank*3+0] = make_float4(mx, my, qa, qb);
        s_params[rank*3+1] = make_float4(qd, wv, r2cut, cr);
        s_params[rank*3+2] = make_float4(cg, cb, 0.f, 0.f);
    }
    __syncthreads();

    // ---------------- phase 2: cull + compact (threads 0..511) -------------
    const float rx0 = (float)x0, ry0 = (float)y0;
    const float rx1 = rx0 + 15.f, ry1 = ry0 + 15.f;

    bool pass = false;
    unsigned long long mm = 0ull;
    float4 p0c = make_float4(0,0,0,0), p1c = make_float4(0,0,0,0);

    if (tid < N_G) {
        p0c = s_params[tid*3];
        p1c = s_params[tid*3+1];
        const float w = p1c.y, rc = p1c.z;
        const float cxp = fminf(fmaxf(p0c.x, rx0), rx1);
        const float cyp = fminf(fmaxf(p0c.y, ry0), ry1);
        const float ddx = p0c.x - cxp, ddy = p0c.y - cyp;
        const float d2 = ddx*ddx + ddy*ddy;
        pass = (w > 0.f) && (d2 <= rc);
        mm = __ballot(pass);
        if (lane == 0) s_cnt[wave] = __popcll(mm);
    }
    __syncthreads();
    if (tid == 0) {
        int acc = 0;
        #pragma unroll
        for (int g = 0; g < 8; ++g) { s_off[g] = acc; acc += s_cnt[g]; }
        s_off[8] = acc;
    }
    __syncthreads();
    if (pass) {
        const int rank = __popcll(mm & ((1ull << lane) - 1ull));
        const int dst = s_off[wave] + rank;
        s_p[dst*3+0] = p0c;
        s_p[dst*3+1] = p1c;
        s_p[dst*3+2] = s_params[tid*3+2];
    }
    __syncthreads();
    const int count = s_off[8];

    // ---------------- phase 3: 4-way segmented composite -------------------
    const int seg = tid >> 8;          // 0..3, depth segment
    const int pix = tid & 255;         // pixel within tile
    const float px = (float)(x0 + (pix & 15));
    const float py = (float)(y0 + (pix >> 4));

    const int j0 = (count * seg)       >> 2;
    const int j1 = (count * (seg + 1)) >> 2;

    float T = 1.f, accr = 0.f, accg = 0.f, accb = 0.f;
    #pragma unroll 4
    for (int j = j0; j < j1; ++j) {
        const float4 p0 = s_p[j*3+0];
        const float4 p1 = s_p[j*3+1];
        const float4 p2 = s_p[j*3+2];
        const float dx = px - p0.x;
        const float dy = py - p0.y;
        const float e = (p0.z*dx + p0.w*dy)*dx + p1.x*dy*dy;
        const float alpha = p1.y * __expf(e);
        const float wt = alpha * T;
        accr = fmaf(wt, p1.w, accr);
        accg = fmaf(wt, p2.x, accg);
        accb = fmaf(wt, p2.y, accb);
        T = fmaf(-alpha, T, T);
    }

    if (seg > 0) s_part[(seg-1)*256 + pix] = make_float4(accr, accg, accb, T);
    __syncthreads();

    if (seg == 0) {
        #pragma unroll
        for (int s2 = 0; s2 < 3; ++s2) {
            const float4 q = s_part[s2*256 + pix];
            accr = fmaf(T, q.x, accr);
            accg = fmaf(T, q.y, accg);
            accb = fmaf(T, q.z, accb);
            T *= q.w;
        }
        const int o = ((y0 + (pix >> 4)) * W_IMG + (x0 + (pix & 15))) * 3;
        out[o+0] = accr;
        out[o+1] = accg;
        out[o+2] = accb;
    }
}

extern "C" void kernel_launch(void* const* d_in, const int* in_sizes, int n_in,
                              void* d_out, int out_size, void* d_ws, size_t ws_size,
                              hipStream_t stream) {
    const float* means3D = (const float*)d_in[0];
    const float* covs3d  = (const float*)d_in[1];
    const float* colors  = (const float*)d_in[2];
    const float* opac    = (const float*)d_in[3];
    const float* Km      = (const float*)d_in[4];
    const float* Rm      = (const float*)d_in[5];
    const float* tv      = (const float*)d_in[6];
    // d_in[7] = pixels: exact integer meshgrid, regenerated in-kernel

    hipLaunchKernelGGL(gs_fused, dim3(W_IMG/16, H_IMG/16), dim3(1024), 0, stream,
                       means3D, covs3d, colors, opac, Km, Rm, tv, (float*)d_out);
}